// Round 8
// baseline (754.290 us; speedup 1.0000x reference)
//
#include <hip/hip_runtime.h>
#include <stdint.h>

#define C 512
#define C2 262144  // 512*512

typedef __attribute__((ext_vector_type(8))) short bf16x8;
typedef __attribute__((ext_vector_type(4))) float f32x4;

__device__ __forceinline__ unsigned short f2bf(float f) {
    union { float f; uint32_t u; } v; v.f = f;
    uint32_t u = v.u;
    u += 0x7fffu + ((u >> 16) & 1u);   // round-to-nearest-even
    return (unsigned short)(u >> 16);
}
__device__ __forceinline__ float bf2f(unsigned short h) {
    union { uint32_t u; float f; } v; v.u = ((uint32_t)h) << 16;
    return v.f;
}

#define GL2LDS16(g, l) __builtin_amdgcn_global_load_lds( \
    (const __attribute__((address_space(1))) void*)(g),  \
    (__attribute__((address_space(3))) void*)(l), 16, 0, 0)

__device__ __forceinline__ bf16x8 ldsr16(const char* p) {
    bf16x8 r;
    asm volatile("ds_read_b128 %0, %1"
                 : "=v"(r)
                 : "v"((__attribute__((address_space(3))) const void*)p));
    return r;
}

__device__ __forceinline__ int nth_valid(int mask, int n) {
    int pq = 0;
    while (true) {
        if (mask & 1) { if (n == 0) return pq; --n; }
        mask >>= 1; ++pq;
    }
}

// K [o][i][3][3] fp32 ->
//   Kt  bf16 [j][o][c] = K[o][c][j]   (GEMM B operand)
//   KtT bf16 [j][i][c] = K[c][i][j]   (step-2 GEMM A operand = Ki1^T)
//   Ktf f32  [j][i][o] = K[o][i][j]   (assembly K-term, coalesced in o)
__global__ void k_transform(const float* __restrict__ K,
                            unsigned short* __restrict__ Kt,
                            unsigned short* __restrict__ KtT,
                            float* __restrict__ Ktf) {
    int t = blockIdx.x * 256 + threadIdx.x;  // t = a*512 + b
    int a = t >> 9, b = t & 511;
#pragma unroll
    for (int j = 0; j < 9; ++j) {
        float v = K[(size_t)t * 9 + j];
        unsigned short h = f2bf(v);
        Kt[(size_t)j * C2 + t] = h;
        KtT[(size_t)j * C2 + (size_t)b * C + a] = h;
        Ktf[(size_t)j * C2 + (size_t)b * C + a] = v;
    }
}

// Parallel heavy-first work-list build + counter zeroing.
__global__ void k_sched(int* __restrict__ sched) {
    __shared__ int hist[4][10];
    __shared__ int base[4][10];
    const int tid = threadIdx.x;
    if (tid < 40) ((int*)hist)[tid] = 0;
    if (tid < 4) sched[tid] = 0;
    __syncthreads();
    const int offs[5] = {0, 25, 74, 155, 276};
    int step = -1, yx = 0, V = 0;
    if (tid < 276) {
#pragma unroll
        for (int s = 0; s < 4; ++s)
            if (tid >= offs[s] && tid < offs[s + 1]) { step = s; yx = tid - offs[s]; }
        const int s_out = 5 + 2 * step, s_in = s_out - 2;
        const int y = yx / s_out, x = yx % s_out;
        int vy = 0, vx = 0;
#pragma unroll
        for (int p = 0; p < 3; ++p) {
            if (y - p >= 0 && y - p < s_in) ++vy;
            if (x - p >= 0 && x - p < s_in) ++vx;
        }
        V = vy * vx;
        atomicAdd(&hist[step][V], 1);
    }
    __syncthreads();
    if (tid < 4) {
        int acc = 0;
        for (int v = 9; v >= 1; --v) { base[tid][v] = acc; acc += hist[tid][v]; }
        for (int v = 1; v <= 9; ++v) hist[tid][v] = 0;   // reuse as cursor
    }
    __syncthreads();
    if (tid < 276) {
        const int idx = atomicAdd(&hist[step][V], 1);
        const int slot = base[step][V] + idx;
        int* list = sched + 4 + step * 484;
        list[slot * 4 + 0] = yx * 4 + 0;
        list[slot * 4 + 1] = yx * 4 + 1;
        list[slot * 4 + 2] = yx * 4 + 2;
        list[slot * 4 + 3] = yx * 4 + 3;
    }
}

// Persistent-block 256x256-tile 8-phase MFMA GEMM, full one-phase-ahead
// prefetch: B frags reg-double-buffered (bB0/bB1), A quads alternating
// (aE/aO). Per-phase lgkmcnt == reads issued THAT phase -> the wait drains
// exactly the previous phase's reads; no phase blocks on its own reads.
// LDS slots: B0@0, A0@32768, B1@65536, A1@98304 (each 2x16KB halves),
// dump@131072. Stages: ph0 A1(same iter par1), ph1 B0', ph4 A0', ph5 B1'.
// vmcnt: end-ph1(8), end-ph2(4), end-ph5(8), end-ph6(4).
__global__ __launch_bounds__(512, 2) void k_gemm(
    const unsigned short* __restrict__ A,   // [s_in^2][512 i][512 c] bf16
    const unsigned short* __restrict__ Bm,  // [9][512 o][512 c] bf16
    unsigned short* __restrict__ Out,       // [s_out^2][512 i][512 o] bf16
    int s_in, int s_out, float alpha,
    int* __restrict__ ctr, const int* __restrict__ list, int n_items)
{
    __shared__ __align__(16) char lds[147456];
    __shared__ int s_item;

    const int tid = threadIdx.x;
    const int lane = tid & 63, wid = tid >> 6;
    const int wr = wid >> 2, wc = wid & 3;        // 2(M) x 4(N) waves
    const int l15 = lane & 15, lhi = lane >> 4;

    const int srow = tid >> 3, scol = tid & 7;
    const int soff0 = srow * 1024 + ((scol ^ (srow & 7)) * 16);
    const int soff1 = soff0 + 65536;       // +64 rows: (row&7) unchanged
    const int t16 = tid * 16;

    const int swz = (l15 & 7) << 4;
    const int coff0 = (lhi * 16) ^ swz;          // kk=0
    const int coff1 = (64 + lhi * 16) ^ swz;     // kk=1
    const int bbase = ((wc >> 1) * 16384) + ((wc & 1) * 64 + l15) * 128;
    const int abase = 32768 + wr * 16384 + l15 * 128;

    const char* Abase = (const char*)A;
    const char* Bbase = (const char*)Bm;

    for (;;) {
        __syncthreads();                       // drains all counters too
        if (tid == 0) s_item = atomicAdd(ctr, 1);
        __syncthreads();
        const int itm = s_item;
        if (itm >= n_items) break;
        const int code = list[itm];
        const int yx = code >> 2, quad = code & 3;
        const int i0 = (quad & 1) * 256, o0 = (quad >> 1) * 256;
        const int y = yx / s_out, x = yx % s_out;

        int mask = 0, V = 0;
        for (int pq = 0; pq < 9; ++pq) {
            int u = y - pq / 3, v = x - pq % 3;
            if (u >= 0 && u < s_in && v >= 0 && v < s_in) { mask |= 1 << pq; ++V; }
        }

        auto slabA = [&](int pq) {
            int u = y - pq / 3, v = x - pq % 3;
            return Abase + ((size_t)(u * s_in + v) * C + i0) * (size_t)(C * 2);
        };
        auto slabB = [&](int pq) {
            return Bbase + ((size_t)pq * C + o0) * (size_t)(C * 2);
        };
        const int pq0 = nth_valid(mask, 0);
        const char* curA = slabA(pq0);
        const char* curB = slabB(pq0);
        const char* nxtA = curA;
        const char* nxtB = curB;
        if (V > 1) { int p1 = nth_valid(mask, 1); nxtA = slabA(p1); nxtB = slabB(p1); }

        f32x4 acc[8][4] = {};
        bf16x8 bB0[8], bB1[8];   // B frags par0 / par1 (reg double-buffer)
        bf16x8 aE[4], aO[4];     // A quad frags, even/odd phase

        // ---- prologue: stage B0<-ks0, A0<-ks0, B1<-ks1 (12 loads) ----
        GL2LDS16(curB + soff0,         lds + t16);
        GL2LDS16(curB + soff1,         lds + 8192 + t16);
        GL2LDS16(curB + 131072 + soff0, lds + 16384 + t16);
        GL2LDS16(curB + 131072 + soff1, lds + 16384 + 8192 + t16);
        GL2LDS16(curA + soff0,         lds + 32768 + t16);
        GL2LDS16(curA + soff1,         lds + 32768 + 8192 + t16);
        GL2LDS16(curA + 131072 + soff0, lds + 49152 + t16);
        GL2LDS16(curA + 131072 + soff1, lds + 49152 + 8192 + t16);
        GL2LDS16(curB + 128 + soff0,         lds + 65536 + t16);
        GL2LDS16(curB + 128 + soff1,         lds + 65536 + 8192 + t16);
        GL2LDS16(curB + 128 + 131072 + soff0, lds + 81920 + t16);
        GL2LDS16(curB + 128 + 131072 + soff1, lds + 81920 + 8192 + t16);
        asm volatile("s_waitcnt vmcnt(4)" ::: "memory");  // B0+A0 landed, B1 in flight
        __builtin_amdgcn_s_barrier();
        __builtin_amdgcn_sched_barrier(0);
        // prologue reads: bB0 (8) + aE=par0 q0 (4); drain fully
#pragma unroll
        for (int n = 0; n < 4; ++n) {
            bB0[n * 2 + 0] = ldsr16(lds + bbase + n * 2048 + coff0);
            bB0[n * 2 + 1] = ldsr16(lds + bbase + n * 2048 + coff1);
        }
#pragma unroll
        for (int mi = 0; mi < 2; ++mi) {
            aE[mi * 2 + 0] = ldsr16(lds + abase + mi * 2048 + coff0);
            aE[mi * 2 + 1] = ldsr16(lds + abase + mi * 2048 + coff1);
        }
        asm volatile("s_waitcnt lgkmcnt(0)" ::: "memory");
        __builtin_amdgcn_sched_barrier(0);

#define STAGEPAIR(SRC, DSTOFF) { \
        const char* s0_ = (SRC); \
        char* d0_ = dummy ? (lds + 131072) : (lds + (DSTOFF)); \
        char* d1_ = dummy ? (lds + 131072) : (lds + (DSTOFF) + 16384); \
        GL2LDS16(s0_ + soff0,          d0_ + t16); \
        GL2LDS16(s0_ + soff1,          d0_ + 8192 + t16); \
        GL2LDS16(s0_ + 131072 + soff0, d1_ + t16); \
        GL2LDS16(s0_ + 131072 + soff1, d1_ + 8192 + t16); \
    }
#define STAGEPAIR_CUR(SRC, DSTOFF) { \
        const char* s0_ = (SRC); \
        GL2LDS16(s0_ + soff0,          lds + (DSTOFF) + t16); \
        GL2LDS16(s0_ + soff1,          lds + (DSTOFF) + 8192 + t16); \
        GL2LDS16(s0_ + 131072 + soff0, lds + (DSTOFF) + 16384 + t16); \
        GL2LDS16(s0_ + 131072 + soff1, lds + (DSTOFF) + 16384 + 8192 + t16); \
    }
#define MFBLK(AARR, BARR, QQ) \
        _Pragma("unroll") for (int mi = 0; mi < 2; ++mi) \
        _Pragma("unroll") for (int n = 0; n < 4; ++n) { \
            acc[(QQ) * 2 + mi][n] = __builtin_amdgcn_mfma_f32_16x16x32_bf16( \
                AARR[mi * 2 + 0], BARR[n * 2 + 0], acc[(QQ) * 2 + mi][n], 0, 0, 0); \
            acc[(QQ) * 2 + mi][n] = __builtin_amdgcn_mfma_f32_16x16x32_bf16( \
                AARR[mi * 2 + 1], BARR[n * 2 + 1], acc[(QQ) * 2 + mi][n], 0, 0, 0); \
        }

        const int NI = 4 * V;
        for (int it = 0; it < NI; ++it) {
            const int itl = it & 3;
            const bool lastq = (itl == 3);
            const bool dummy = lastq && (((it >> 2) + 1) >= V);
            const char* sAe = lastq ? nxtA : curA;
            const char* sBe = lastq ? nxtB : curB;
            const int c1  = (2 * itl + 1) * 128;               // A1: this iter par1
            const int cse = lastq ? 0 : (2 * itl + 2) * 128;   // next iter par0
            const int cso = cse + 128;                         // next iter par1

#define PHASE(PH) { \
        constexpr int q_ = (PH) & 3, par_ = (PH) >> 2; \
        constexpr int aq_ = ((PH) + 1) & 3; \
        constexpr int apar_ = ((PH) <= 2) ? 0 : (((PH) <= 6) ? 1 : 0); \
        /* A-quad prefetch (4 reads) into the non-current reg set */ \
        _Pragma("unroll") for (int mi = 0; mi < 2; ++mi) { \
            bf16x8 t0 = ldsr16(lds + apar_ * 65536 + abase + aq_ * 4096 + mi * 2048 + coff0); \
            bf16x8 t1 = ldsr16(lds + apar_ * 65536 + abase + aq_ * 4096 + mi * 2048 + coff1); \
            if constexpr (((PH) & 1) == 0) { aO[mi * 2 + 0] = t0; aO[mi * 2 + 1] = t1; } \
            else                           { aE[mi * 2 + 0] = t0; aE[mi * 2 + 1] = t1; } \
        } \
        /* B-frag prefetch (4 reads) on ph2/3 (par1) and ph6/7 (next par0) */ \
        if constexpr ((PH) == 2 || (PH) == 3 || (PH) == 6 || (PH) == 7) { \
            constexpr int nb_ = ((PH) & 1) ? 2 : 0; \
            _Pragma("unroll") for (int n = nb_; n < nb_ + 2; ++n) { \
                bf16x8 t0 = ldsr16(lds + ((PH) < 4 ? 65536 : 0) + bbase + n * 2048 + coff0); \
                bf16x8 t1 = ldsr16(lds + ((PH) < 4 ? 65536 : 0) + bbase + n * 2048 + coff1); \
                if constexpr ((PH) < 4) { bB1[n * 2 + 0] = t0; bB1[n * 2 + 1] = t1; } \
                else                    { bB0[n * 2 + 0] = t0; bB0[n * 2 + 1] = t1; } \
            } \
        } \
        asm volatile("" ::: "memory"); \
        if constexpr ((PH) == 0) STAGEPAIR_CUR(curA + c1, 98304)  /* A1 */ \
        if constexpr ((PH) == 1) STAGEPAIR(sBe + cse, 0)          /* B0' */ \
        if constexpr ((PH) == 4) STAGEPAIR(sAe + cse, 32768)      /* A0' */ \
        if constexpr ((PH) == 5) STAGEPAIR(sBe + cso, 65536)      /* B1' */ \
        __builtin_amdgcn_s_barrier(); \
        if constexpr ((PH) == 2 || (PH) == 3 || (PH) == 6 || (PH) == 7) { \
            asm volatile("s_waitcnt lgkmcnt(8)" ::: "memory"); \
        } else { \
            asm volatile("s_waitcnt lgkmcnt(4)" ::: "memory"); \
        } \
        __builtin_amdgcn_sched_barrier(0); \
        __builtin_amdgcn_s_setprio(1); \
        if constexpr (((PH) & 1) == 0 && par_ == 0)      MFBLK(aE, bB0, q_) \
        else if constexpr (((PH) & 1) == 1 && par_ == 0) MFBLK(aO, bB0, q_) \
        else if constexpr (((PH) & 1) == 0 && par_ == 1) MFBLK(aE, bB1, q_) \
        else                                             MFBLK(aO, bB1, q_) \
        __builtin_amdgcn_s_setprio(0); \
        if constexpr ((PH) == 1 || (PH) == 5) { \
            asm volatile("s_waitcnt vmcnt(8)" ::: "memory"); \
        } \
        if constexpr ((PH) == 2 || (PH) == 6) { \
            asm volatile("s_waitcnt vmcnt(4)" ::: "memory"); \
        } \
        __builtin_amdgcn_s_barrier(); \
        __builtin_amdgcn_sched_barrier(0); \
    }

            PHASE(0) PHASE(1) PHASE(2) PHASE(3)
            PHASE(4) PHASE(5) PHASE(6) PHASE(7)
#undef PHASE

            if (lastq) {
                curA = nxtA; curB = nxtB;
                int vn = (it >> 2) + 2;
                if (vn < V) {
                    int pqn = nth_valid(mask, vn);
                    nxtA = slabA(pqn); nxtB = slabB(pqn);
                }
            }
        }
#undef STAGEPAIR
#undef STAGEPAIR_CUR
#undef MFBLK

        // D layout per 16x16 frag: col(o)=lane&15, row(i)=(lane>>4)*4+reg
#pragma unroll
        for (int M = 0; M < 8; ++M) {
#pragma unroll
            for (int r = 0; r < 4; ++r) {
                const int irow = i0 + wr * 128 + M * 16 + lhi * 4 + r;
                unsigned short* op = Out + ((size_t)yx * C + irow) * C
                                   + o0 + wc * 64 + l15;
#pragma unroll
                for (int n = 0; n < 4; ++n)
                    op[n * 16] = f2bf(acc[M][n][r] * alpha);
            }
        }
    }
    asm volatile("s_waitcnt vmcnt(0)" ::: "memory");  // drain tail dummies
}

// Two-source assembly (fallback path).
__global__ __launch_bounds__(256) void k_final(
    const unsigned short* __restrict__ Ka, int sa, int ofa,
    const unsigned short* __restrict__ Kb, int sb, int ofb,
    const float* __restrict__ Ktf, float* __restrict__ kg, int init)
{
    __shared__ float L[64 * 121];
    const int i = blockIdx.x;
    const int o0 = blockIdx.y * 64;
    const int tid = threadIdx.x, lane = tid & 63, wid = tid >> 6;

    for (int idx = tid; idx < 64 * 121; idx += 256) L[idx] = 0.f;
    __syncthreads();

    const int sa2 = sa * sa;
    for (int yxv = wid; yxv < sa2; yxv += 4) {
        float v = bf2f(Ka[((size_t)yxv * C + i) * C + o0 + lane]);
        int yy = yxv / sa + ofa, xx = yxv % sa + ofa;
        L[lane * 121 + yy * 11 + xx] += v;
    }
    __syncthreads();
    const int sb2 = sb * sb;
    for (int yxv = wid; yxv < sb2; yxv += 4) {
        float v = bf2f(Kb[((size_t)yxv * C + i) * C + o0 + lane]);
        int yy = yxv / sb + ofb, xx = yxv % sb + ofb;
        L[lane * 121 + yy * 11 + xx] += v;
    }
    __syncthreads();
    if (init) {
        for (int j = wid; j < 9; j += 4) {
            float v = Ktf[(size_t)j * C2 + (size_t)i * C + o0 + lane];
            if (j == 4 && (o0 + lane) == i) v += 1.0f;
            L[lane * 121 + (j / 3 + 4) * 11 + (j % 3 + 4)] += v;
        }
    }
    __syncthreads();
    if (init) {
        for (int idx = tid; idx < 64 * 121; idx += 256) {
            int ol = idx / 121, w = idx - ol * 121;
            kg[((size_t)(o0 + ol) * C + i) * 121 + w] = L[idx];
        }
    } else {
        for (int idx = tid; idx < 64 * 121; idx += 256) {
            int ol = idx / 121, w = idx - ol * 121;
            kg[((size_t)(o0 + ol) * C + i) * 121 + w] += L[idx];
        }
    }
}

// Fused four-source assembly (big-ws path): kg = I + K + Ki2..Ki5, one pass.
__global__ __launch_bounds__(256) void k_final4(
    const unsigned short* __restrict__ K2, const unsigned short* __restrict__ K3,
    const unsigned short* __restrict__ K4, const unsigned short* __restrict__ K5,
    const float* __restrict__ Ktf, float* __restrict__ kg)
{
    __shared__ float L[64 * 121];
    const int i = blockIdx.x;
    const int o0 = blockIdx.y * 64;
    const int tid = threadIdx.x, lane = tid & 63, wid = tid >> 6;

    for (int idx = tid; idx < 64 * 121; idx += 256) L[idx] = 0.f;
    __syncthreads();

#define ADDSRC(SRC, S, OFS) { \
        const int s2_ = (S) * (S); \
        for (int yxv = wid; yxv < s2_; yxv += 4) { \
            float v = bf2f((SRC)[((size_t)yxv * C + i) * C + o0 + lane]); \
            int yy = yxv / (S) + (OFS), xx = yxv % (S) + (OFS); \
            L[lane * 121 + yy * 11 + xx] += v; \
        } \
        __syncthreads(); \
    }
    ADDSRC(K2, 5, 3) ADDSRC(K3, 7, 2) ADDSRC(K4, 9, 1) ADDSRC(K5, 11, 0)
#undef ADDSRC

    for (int j = wid; j < 9; j += 4) {
        float v = Ktf[(size_t)j * C2 + (size_t)i * C + o0 + lane];
        if (j == 4 && (o0 + lane) == i) v += 1.0f;   // identity at (5,5)
        L[lane * 121 + (j / 3 + 4) * 11 + (j % 3 + 4)] += v;
    }
    __syncthreads();
    for (int idx = tid; idx < 64 * 121; idx += 256) {
        int ol = idx / 121, w = idx - ol * 121;
        kg[((size_t)(o0 + ol) * C + i) * 121 + w] = L[idx];
    }
}

extern "C" void kernel_launch(void* const* d_in, const int* in_sizes, int n_in,
                              void* d_out, int out_size, void* d_ws, size_t ws_size,
                              hipStream_t stream) {
    const float* K = (const float*)d_in[0];
    float* kg = (float*)d_out;
    char* ws = (char*)d_ws;

    unsigned short* Kt  = (unsigned short*)(ws);
    unsigned short* KtT = (unsigned short*)(ws + (size_t)4718592);
    float*          Ktf = (float*)         (ws + (size_t)9437184);

    const bool big = (ws_size >= (size_t)163585616);

    if (big) {
        unsigned short* Ki2 = (unsigned short*)(ws + (size_t)18874368);
        unsigned short* Ki3 = (unsigned short*)(ws + (size_t)31981568);
        unsigned short* Ki4 = (unsigned short*)(ws + (size_t)57671680);
        unsigned short* Ki5 = (unsigned short*)(ws + (size_t)100139008);
        int* sch = (int*)(ws + (size_t)163577856);
        int* ctr = sch;
        int* lst = sch + 4;

        k_transform<<<1024, 256, 0, stream>>>(K, Kt, KtT, Ktf);
        k_sched<<<1, 320, 0, stream>>>(sch);
        k_gemm<<<256, 512, 0, stream>>>(KtT, Kt, Ki2, 3, 5, 0.5f,
                                        ctr + 0, lst + 0 * 484, 100);
        k_gemm<<<256, 512, 0, stream>>>(Ki2, Kt, Ki3, 5, 7, 1.0f / 3.0f,
                                        ctr + 1, lst + 1 * 484, 196);
        k_gemm<<<256, 512, 0, stream>>>(Ki3, Kt, Ki4, 7, 9, 0.25f,
                                        ctr + 2, lst + 2 * 484, 324);
        k_gemm<<<256, 512, 0, stream>>>(Ki4, Kt, Ki5, 9, 11, 0.2f,
                                        ctr + 3, lst + 3 * 484, 484);
        k_final4<<<dim3(512, 8), 256, 0, stream>>>(Ki2, Ki3, Ki4, Ki5, Ktf, kg);
    } else {
        unsigned short* P1 = (unsigned short*)(ws + (size_t)18874368);
        unsigned short* P2 = (unsigned short*)(ws + (size_t)61341696);
        int* sch = (int*)(ws + (size_t)124780544);
        int* ctr = sch;
        int* lst = sch + 4;

        k_transform<<<1024, 256, 0, stream>>>(K, Kt, KtT, Ktf);
        k_sched<<<1, 320, 0, stream>>>(sch);
        k_gemm<<<256, 512, 0, stream>>>(KtT, Kt, P1, 3, 5, 0.5f,
                                        ctr + 0, lst + 0 * 484, 100);
        k_gemm<<<256, 512, 0, stream>>>(P1, Kt, P2, 5, 7, 1.0f / 3.0f,
                                        ctr + 1, lst + 1 * 484, 196);
        k_final<<<dim3(512, 8), 256, 0, stream>>>(P1, 5, 3, P2, 7, 2, Ktf, kg, 1);
        k_gemm<<<256, 512, 0, stream>>>(P2, Kt, P1, 7, 9, 0.25f,
                                        ctr + 2, lst + 2 * 484, 324);
        k_gemm<<<256, 512, 0, stream>>>(P1, Kt, P2, 9, 11, 0.2f,
                                        ctr + 3, lst + 3 * 484, 484);
        k_final<<<dim3(512, 8), 256, 0, stream>>>(P1, 9, 1, P2, 11, 0, Ktf, kg, 0);
    }
}

// Round 9
// 538.374 us; speedup vs baseline: 1.4011x; 1.4011x over previous
//
#include <hip/hip_runtime.h>
#include <stdint.h>

#define C 512
#define C2 262144  // 512*512

typedef __attribute__((ext_vector_type(8))) short bf16x8;
typedef __attribute__((ext_vector_type(4))) float f32x4;

__device__ __forceinline__ unsigned short f2bf(float f) {
    union { float f; uint32_t u; } v; v.f = f;
    uint32_t u = v.u;
    u += 0x7fffu + ((u >> 16) & 1u);   // round-to-nearest-even
    return (unsigned short)(u >> 16);
}
__device__ __forceinline__ float bf2f(unsigned short h) {
    union { uint32_t u; float f; } v; v.u = ((uint32_t)h) << 16;
    return v.f;
}

#define GL2LDS16(g, l) __builtin_amdgcn_global_load_lds( \
    (const __attribute__((address_space(1))) void*)(g),  \
    (__attribute__((address_space(3))) void*)(l), 16, 0, 0)

__device__ __forceinline__ bf16x8 ldsr16(const char* p) {
    bf16x8 r;
    asm volatile("ds_read_b128 %0, %1"
                 : "=v"(r)
                 : "v"((__attribute__((address_space(3))) const void*)p));
    return r;
}

__device__ __forceinline__ int nth_valid(int mask, int n) {
    int pq = 0;
    while (true) {
        if (mask & 1) { if (n == 0) return pq; --n; }
        mask >>= 1; ++pq;
    }
}

// K [o][i][3][3] fp32 ->
//   Kt  bf16 [j][o][c] = K[o][c][j]   (GEMM B operand)
//   KtT bf16 [j][i][c] = K[c][i][j]   (step-2 GEMM A operand = Ki1^T)
//   Ktf f32  [j][i][o] = K[o][i][j]   (assembly K-term, coalesced in o)
__global__ void k_transform(const float* __restrict__ K,
                            unsigned short* __restrict__ Kt,
                            unsigned short* __restrict__ KtT,
                            float* __restrict__ Ktf) {
    int t = blockIdx.x * 256 + threadIdx.x;  // t = a*512 + b
    int a = t >> 9, b = t & 511;
#pragma unroll
    for (int j = 0; j < 9; ++j) {
        float v = K[(size_t)t * 9 + j];
        unsigned short h = f2bf(v);
        Kt[(size_t)j * C2 + t] = h;
        KtT[(size_t)j * C2 + (size_t)b * C + a] = h;
        Ktf[(size_t)j * C2 + (size_t)b * C + a] = v;
    }
}

// Parallel heavy-first work-list build (one entry per yx; item = yx*16+quad).
// sched layout: int ctr[4]; 4 lists of up to 484 ints (stride 484).
__global__ void k_sched(int* __restrict__ sched) {
    __shared__ int hist[4][10];
    __shared__ int base[4][10];
    const int tid = threadIdx.x;
    if (tid < 40) ((int*)hist)[tid] = 0;
    if (tid < 4) sched[tid] = 0;
    __syncthreads();
    const int offs[5] = {0, 25, 74, 155, 276};
    int step = -1, yx = 0, V = 0;
    if (tid < 276) {
#pragma unroll
        for (int s = 0; s < 4; ++s)
            if (tid >= offs[s] && tid < offs[s + 1]) { step = s; yx = tid - offs[s]; }
        const int s_out = 5 + 2 * step, s_in = s_out - 2;
        const int y = yx / s_out, x = yx % s_out;
        int vy = 0, vx = 0;
#pragma unroll
        for (int p = 0; p < 3; ++p) {
            if (y - p >= 0 && y - p < s_in) ++vy;
            if (x - p >= 0 && x - p < s_in) ++vx;
        }
        V = vy * vx;
        atomicAdd(&hist[step][V], 1);
    }
    __syncthreads();
    if (tid < 4) {
        int acc = 0;
        for (int v = 9; v >= 1; --v) { base[tid][v] = acc; acc += hist[tid][v]; }
        for (int v = 1; v <= 9; ++v) hist[tid][v] = 0;   // reuse as cursor
    }
    __syncthreads();
    if (tid < 276) {
        const int idx = atomicAdd(&hist[step][V], 1);
        sched[4 + step * 484 + base[step][V] + idx] = yx;
    }
}

// Persistent 128x128-tile MFMA GEMM, 256 threads (2x2 waves), BK=64,
// 2 blocks/CU (64KB LDS). 4 phases/iter (2 K-tiles), ONE barrier/phase.
// Invariant: lgkmcnt(0) before every barrier -> all ds_reads drained at
// every barrier; each slot restaged exactly one phase after its last read
// (B0: rd ph3 / st ph0; A0: ph0/ph1; B1: ph1/ph2; A1: ph2/ph3).
// Operands always read one phase ahead (aE/aO, bBa/bBb reg sets).
// vmcnt(4) at end-ph0 (B1,A1 landed) and end-ph2 (B0',A0' landed);
// dummy tail iters skip stages and use vmcnt(0).
__global__ __launch_bounds__(256, 2) void k_gemm(
    const unsigned short* __restrict__ A,   // [s_in^2][512 i][512 c] bf16
    const unsigned short* __restrict__ Bm,  // [9][512 o][512 c] bf16
    unsigned short* __restrict__ Out,       // [s_out^2][512 i][512 o] bf16
    int s_in, int s_out, float alpha,
    int* __restrict__ ctr, const int* __restrict__ list, int n_items)
{
    __shared__ __align__(16) char lds[65536];
    __shared__ int s_item;

    const int tid = threadIdx.x;
    const int lane = tid & 63, wid = tid >> 6;
    const int wr = wid >> 1, wc = wid & 1;        // 2(M) x 2(N) waves
    const int l15 = lane & 15, lhi = lane >> 4;

    // staging: thread -> rows (tid>>3)+32*li, 16B-block pre-swizzled so that
    // linear LDS dest + XOR read = consistent involution
    const int soff = (tid >> 3) * 1024 + ((((tid & 7) ^ ((tid >> 3) & 7))) << 4);
    const int t16 = tid * 16;

    // fragment-read constants (swizzled, row stride 128B = 8 16B blocks)
    const int coff0 = ((lhi ^ (l15 & 7)) << 4);        // kk=0
    const int coff1 = (((lhi + 4) ^ (l15 & 7)) << 4);  // kk=1
    const int arow = (wr * 64 + l15) * 128;
    const int brow = (wc * 64 + l15) * 128;

    const char* Abase = (const char*)A;
    const char* Bbase = (const char*)Bm;

#define STAGE4(SRC, SLOT) { \
        const char* s_ = (SRC) + soff; \
        GL2LDS16(s_,         lds + (SLOT) + t16); \
        GL2LDS16(s_ + 32768, lds + (SLOT) + 4096 + t16); \
        GL2LDS16(s_ + 65536, lds + (SLOT) + 8192 + t16); \
        GL2LDS16(s_ + 98304, lds + (SLOT) + 12288 + t16); \
    }

    for (;;) {
        __syncthreads();
        if (tid == 0) s_item = atomicAdd(ctr, 1);
        __syncthreads();
        const int itm = s_item;
        if (itm >= n_items) break;
        const int yx = list[itm >> 4];
        const int quad = itm & 15;
        const int i0 = (quad & 3) * 128, o0 = (quad >> 2) * 128;
        const int y = yx / s_out, x = yx % s_out;

        int mask = 0, V = 0;
        for (int pq = 0; pq < 9; ++pq) {
            int u = y - pq / 3, v = x - pq % 3;
            if (u >= 0 && u < s_in && v >= 0 && v < s_in) { mask |= 1 << pq; ++V; }
        }

        auto slabA = [&](int pq) {
            int u = y - pq / 3, v = x - pq % 3;
            return Abase + ((size_t)(u * s_in + v) * C + i0) * (size_t)(C * 2);
        };
        auto slabB = [&](int pq) {
            return Bbase + ((size_t)pq * C + o0) * (size_t)(C * 2);
        };
        const int pq0 = nth_valid(mask, 0);
        const char* curA = slabA(pq0);
        const char* curB = slabB(pq0);
        const char* nxtA = curA;
        const char* nxtB = curB;
        if (V > 1) { int p1 = nth_valid(mask, 1); nxtA = slabA(p1); nxtB = slabB(p1); }

        f32x4 acc[4][4] = {};
        bf16x8 bBa[8], bBb[8];   // B frags par0 / par1
        bf16x8 aE[4], aO[4];     // A pair frags (even/odd phase consumers)

        // ---- prologue: stage all 4 slots (K-tiles 0,1), then preload ----
        STAGE4(curB,       0)        // B0
        STAGE4(curA,       16384)    // A0
        STAGE4(curB + 128, 32768)    // B1
        STAGE4(curA + 128, 49152)    // A1
        asm volatile("s_waitcnt vmcnt(8)" ::: "memory");  // B0,A0 landed
        __builtin_amdgcn_s_barrier();
        __builtin_amdgcn_sched_barrier(0);
#pragma unroll
        for (int n = 0; n < 4; ++n) {
            bBa[n * 2 + 0] = ldsr16(lds + brow + n * 2048 + coff0);
            bBa[n * 2 + 1] = ldsr16(lds + brow + n * 2048 + coff1);
        }
#pragma unroll
        for (int mi = 0; mi < 2; ++mi) {   // A0 pair0 (mi 0,1)
            aE[mi * 2 + 0] = ldsr16(lds + 16384 + arow + mi * 2048 + coff0);
            aE[mi * 2 + 1] = ldsr16(lds + 16384 + arow + mi * 2048 + coff1);
        }
        asm volatile("s_waitcnt lgkmcnt(0)" ::: "memory");
        __builtin_amdgcn_s_barrier();
        __builtin_amdgcn_sched_barrier(0);

        const int NI = 4 * V;
        for (int it = 0; it < NI; ++it) {
            const int itl = it & 3;
            const bool lastq = (itl == 3);
            const bool dummy = lastq && (((it >> 2) + 1) >= V);
            const char* sAe = lastq ? nxtA : curA;
            const char* sBe = lastq ? nxtB : curB;
            const int cse = lastq ? 0 : (2 * itl + 2) * 128;  // next par0 K-tile
            const int cso = cse + 128;                        // next par1 K-tile

#define PHASE(PH) { \
        constexpr int apar_  = ((PH) == 1 || (PH) == 2) ? 1 : 0; \
        constexpr int apair_ = ((PH) == 0 || (PH) == 2) ? 1 : 0; \
        constexpr int aslot_ = apar_ ? 49152 : 16384; \
        /* A prefetch (4 reads) for phase PH+1 */ \
        _Pragma("unroll") for (int mi = 0; mi < 2; ++mi) { \
            bf16x8 t0 = ldsr16(lds + aslot_ + arow + apair_ * 4096 + mi * 2048 + coff0); \
            bf16x8 t1 = ldsr16(lds + aslot_ + arow + apair_ * 4096 + mi * 2048 + coff1); \
            if constexpr (((PH) & 1) == 0) { aO[mi * 2 + 0] = t0; aO[mi * 2 + 1] = t1; } \
            else                           { aE[mi * 2 + 0] = t0; aE[mi * 2 + 1] = t1; } \
        } \
        /* B prefetch (8 reads): ph1 -> bBb (B1), ph3 -> bBa (B0 of next iter) */ \
        if constexpr ((PH) == 1 || (PH) == 3) { \
            constexpr int bslot_ = ((PH) == 1) ? 32768 : 0; \
            _Pragma("unroll") for (int n = 0; n < 4; ++n) { \
                bf16x8 t0 = ldsr16(lds + bslot_ + brow + n * 2048 + coff0); \
                bf16x8 t1 = ldsr16(lds + bslot_ + brow + n * 2048 + coff1); \
                if constexpr ((PH) == 1) { bBb[n * 2 + 0] = t0; bBb[n * 2 + 1] = t1; } \
                else                     { bBa[n * 2 + 0] = t0; bBa[n * 2 + 1] = t1; } \
            } \
        } \
        asm volatile("" ::: "memory"); \
        if (!dummy) { \
            if constexpr ((PH) == 0) STAGE4(sBe + cse, 0)      /* B0' */ \
            if constexpr ((PH) == 1) STAGE4(sAe + cse, 16384)  /* A0' */ \
            if constexpr ((PH) == 2) STAGE4(sBe + cso, 32768)  /* B1' */ \
            if constexpr ((PH) == 3) STAGE4(sAe + cso, 49152)  /* A1' */ \
        } \
        __builtin_amdgcn_sched_barrier(0); \
        __builtin_amdgcn_s_setprio(1); \
        _Pragma("unroll") for (int mi = 0; mi < 2; ++mi) \
        _Pragma("unroll") for (int n = 0; n < 4; ++n) { \
            if constexpr (((PH) & 1) == 0 && (PH) < 2) { \
                acc[mi][n] = __builtin_amdgcn_mfma_f32_16x16x32_bf16(aE[mi*2+0], bBa[n*2+0], acc[mi][n], 0, 0, 0); \
                acc[mi][n] = __builtin_amdgcn_mfma_f32_16x16x32_bf16(aE[mi*2+1], bBa[n*2+1], acc[mi][n], 0, 0, 0); \
            } else if constexpr (((PH) & 1) == 1 && (PH) < 2) { \
                acc[2+mi][n] = __builtin_amdgcn_mfma_f32_16x16x32_bf16(aO[mi*2+0], bBa[n*2+0], acc[2+mi][n], 0, 0, 0); \
                acc[2+mi][n] = __builtin_amdgcn_mfma_f32_16x16x32_bf16(aO[mi*2+1], bBa[n*2+1], acc[2+mi][n], 0, 0, 0); \
            } else if constexpr (((PH) & 1) == 0) { \
                acc[mi][n] = __builtin_amdgcn_mfma_f32_16x16x32_bf16(aE[mi*2+0], bBb[n*2+0], acc[mi][n], 0, 0, 0); \
                acc[mi][n] = __builtin_amdgcn_mfma_f32_16x16x32_bf16(aE[mi*2+1], bBb[n*2+1], acc[mi][n], 0, 0, 0); \
            } else { \
                acc[2+mi][n] = __builtin_amdgcn_mfma_f32_16x16x32_bf16(aO[mi*2+0], bBb[n*2+0], acc[2+mi][n], 0, 0, 0); \
                acc[2+mi][n] = __builtin_amdgcn_mfma_f32_16x16x32_bf16(aO[mi*2+1], bBb[n*2+1], acc[2+mi][n], 0, 0, 0); \
            } \
        } \
        __builtin_amdgcn_s_setprio(0); \
        asm volatile("s_waitcnt lgkmcnt(0)" ::: "memory"); \
        if constexpr ((PH) == 0 || (PH) == 2) { \
            if (dummy) { asm volatile("s_waitcnt vmcnt(0)" ::: "memory"); } \
            else       { asm volatile("s_waitcnt vmcnt(4)" ::: "memory"); } \
        } \
        __builtin_amdgcn_s_barrier(); \
        __builtin_amdgcn_sched_barrier(0); \
    }

            PHASE(0) PHASE(1) PHASE(2) PHASE(3)
#undef PHASE

            if (lastq) {
                curA = nxtA; curB = nxtB;
                int vn = (it >> 2) + 2;
                if (vn < V) {
                    int pqn = nth_valid(mask, vn);
                    nxtA = slabA(pqn); nxtB = slabB(pqn);
                }
            }
        }

        // D layout per 16x16 frag: col(o)=lane&15, row(i)=(lane>>4)*4+reg
#pragma unroll
        for (int M = 0; M < 4; ++M) {
#pragma unroll
            for (int r = 0; r < 4; ++r) {
                const int irow = i0 + wr * 64 + M * 16 + lhi * 4 + r;
                unsigned short* op = Out + ((size_t)yx * C + irow) * C
                                   + o0 + wc * 64 + l15;
#pragma unroll
                for (int n = 0; n < 4; ++n)
                    op[n * 16] = f2bf(acc[M][n][r] * alpha);
            }
        }
    }
#undef STAGE4
    asm volatile("s_waitcnt vmcnt(0)" ::: "memory");
}

// Two-source assembly (fallback path).
__global__ __launch_bounds__(256) void k_final(
    const unsigned short* __restrict__ Ka, int sa, int ofa,
    const unsigned short* __restrict__ Kb, int sb, int ofb,
    const float* __restrict__ Ktf, float* __restrict__ kg, int init)
{
    __shared__ float L[64 * 121];
    const int i = blockIdx.x;
    const int o0 = blockIdx.y * 64;
    const int tid = threadIdx.x, lane = tid & 63, wid = tid >> 6;

    for (int idx = tid; idx < 64 * 121; idx += 256) L[idx] = 0.f;
    __syncthreads();

    const int sa2 = sa * sa;
    for (int yxv = wid; yxv < sa2; yxv += 4) {
        float v = bf2f(Ka[((size_t)yxv * C + i) * C + o0 + lane]);
        int yy = yxv / sa + ofa, xx = yxv % sa + ofa;
        L[lane * 121 + yy * 11 + xx] += v;
    }
    __syncthreads();
    const int sb2 = sb * sb;
    for (int yxv = wid; yxv < sb2; yxv += 4) {
        float v = bf2f(Kb[((size_t)yxv * C + i) * C + o0 + lane]);
        int yy = yxv / sb + ofb, xx = yxv % sb + ofb;
        L[lane * 121 + yy * 11 + xx] += v;
    }
    __syncthreads();
    if (init) {
        for (int j = wid; j < 9; j += 4) {
            float v = Ktf[(size_t)j * C2 + (size_t)i * C + o0 + lane];
            if (j == 4 && (o0 + lane) == i) v += 1.0f;
            L[lane * 121 + (j / 3 + 4) * 11 + (j % 3 + 4)] += v;
        }
    }
    __syncthreads();
    if (init) {
        for (int idx = tid; idx < 64 * 121; idx += 256) {
            int ol = idx / 121, w = idx - ol * 121;
            kg[((size_t)(o0 + ol) * C + i) * 121 + w] = L[idx];
        }
    } else {
        for (int idx = tid; idx < 64 * 121; idx += 256) {
            int ol = idx / 121, w = idx - ol * 121;
            kg[((size_t)(o0 + ol) * C + i) * 121 + w] += L[idx];
        }
    }
}

// Fused four-source assembly (big-ws path): kg = I + K + Ki2..Ki5, one pass.
__global__ __launch_bounds__(256) void k_final4(
    const unsigned short* __restrict__ K2, const unsigned short* __restrict__ K3,
    const unsigned short* __restrict__ K4, const unsigned short* __restrict__ K5,
    const float* __restrict__ Ktf, float* __restrict__ kg)
{
    __shared__ float L[64 * 121];
    const int i = blockIdx.x;
    const int o0 = blockIdx.y * 64;
    const int tid = threadIdx.x, lane = tid & 63, wid = tid >> 6;

    for (int idx = tid; idx < 64 * 121; idx += 256) L[idx] = 0.f;
    __syncthreads();

#define ADDSRC(SRC, S, OFS) { \
        const int s2_ = (S) * (S); \
        for (int yxv = wid; yxv < s2_; yxv += 4) { \
            float v = bf2f((SRC)[((size_t)yxv * C + i) * C + o0 + lane]); \
            int yy = yxv / (S) + (OFS), xx = yxv % (S) + (OFS); \
            L[lane * 121 + yy * 11 + xx] += v; \
        } \
        __syncthreads(); \
    }
    ADDSRC(K2, 5, 3) ADDSRC(K3, 7, 2) ADDSRC(K4, 9, 1) ADDSRC(K5, 11, 0)
#undef ADDSRC

    for (int j = wid; j < 9; j += 4) {
        float v = Ktf[(size_t)j * C2 + (size_t)i * C + o0 + lane];
        if (j == 4 && (o0 + lane) == i) v += 1.0f;   // identity at (5,5)
        L[lane * 121 + (j / 3 + 4) * 11 + (j % 3 + 4)] += v;
    }
    __syncthreads();
    for (int idx = tid; idx < 64 * 121; idx += 256) {
        int ol = idx / 121, w = idx - ol * 121;
        kg[((size_t)(o0 + ol) * C + i) * 121 + w] = L[idx];
    }
}

extern "C" void kernel_launch(void* const* d_in, const int* in_sizes, int n_in,
                              void* d_out, int out_size, void* d_ws, size_t ws_size,
                              hipStream_t stream) {
    const float* K = (const float*)d_in[0];
    float* kg = (float*)d_out;
    char* ws = (char*)d_ws;

    unsigned short* Kt  = (unsigned short*)(ws);
    unsigned short* KtT = (unsigned short*)(ws + (size_t)4718592);
    float*          Ktf = (float*)         (ws + (size_t)9437184);

    const bool big = (ws_size >= (size_t)163585616);

    if (big) {
        unsigned short* Ki2 = (unsigned short*)(ws + (size_t)18874368);
        unsigned short* Ki3 = (unsigned short*)(ws + (size_t)31981568);
        unsigned short* Ki4 = (unsigned short*)(ws + (size_t)57671680);
        unsigned short* Ki5 = (unsigned short*)(ws + (size_t)100139008);
        int* sch = (int*)(ws + (size_t)163577856);
        int* ctr = sch;
        int* lst = sch + 4;

        k_transform<<<1024, 256, 0, stream>>>(K, Kt, KtT, Ktf);
        k_sched<<<1, 320, 0, stream>>>(sch);
        k_gemm<<<512, 256, 0, stream>>>(KtT, Kt, Ki2, 3, 5, 0.5f,
                                        ctr + 0, lst + 0 * 484, 400);
        k_gemm<<<512, 256, 0, stream>>>(Ki2, Kt, Ki3, 5, 7, 1.0f / 3.0f,
                                        ctr + 1, lst + 1 * 484, 784);
        k_gemm<<<512, 256, 0, stream>>>(Ki3, Kt, Ki4, 7, 9, 0.25f,
                                        ctr + 2, lst + 2 * 484, 1296);
        k_gemm<<<512, 256, 0, stream>>>(Ki4, Kt, Ki5, 9, 11, 0.2f,
                                        ctr + 3, lst + 3 * 484, 1936);
        k_final4<<<dim3(512, 8), 256, 0, stream>>>(Ki2, Ki3, Ki4, Ki5, Ktf, kg);
    } else {
        unsigned short* P1 = (unsigned short*)(ws + (size_t)18874368);
        unsigned short* P2 = (unsigned short*)(ws + (size_t)61341696);
        int* sch = (int*)(ws + (size_t)124780544);
        int* ctr = sch;
        int* lst = sch + 4;

        k_transform<<<1024, 256, 0, stream>>>(K, Kt, KtT, Ktf);
        k_sched<<<1, 320, 0, stream>>>(sch);
        k_gemm<<<512, 256, 0, stream>>>(KtT, Kt, P1, 3, 5, 0.5f,
                                        ctr + 0, lst + 0 * 484, 400);
        k_gemm<<<512, 256, 0, stream>>>(P1, Kt, P2, 5, 7, 1.0f / 3.0f,
                                        ctr + 1, lst + 1 * 484, 784);
        k_final<<<dim3(512, 8), 256, 0, stream>>>(P1, 5, 3, P2, 7, 2, Ktf, kg, 1);
        k_gemm<<<512, 256, 0, stream>>>(P2, Kt, P1, 7, 9, 0.25f,
                                        ctr + 2, lst + 2 * 484, 1296);
        k_gemm<<<512, 256, 0, stream>>>(P1, Kt, P2, 9, 11, 0.2f,
                                        ctr + 3, lst + 3 * 484, 1936);
        k_final<<<dim3(512, 8), 256, 0, stream>>>(P1, 9, 1, P2, 11, 0, Ktf, kg, 0);
    }
}